// Round 3
// baseline (16.325 us; speedup 1.0000x reference)
//
#include <hip/hip_runtime.h>

#define B_N 8192
#define R_N 256
#define A_N 64
#define KB 16   // k-values per block

// Lane r = threadIdx.x owns rule r (4 waves x 64 rules). Block owns KB k's.
// Aliveness: w > 0  <=>  for all dims: a < x < d  (exact for a<b<c<d a.s.)
// Hot loop: x via wave-uniform s_load (prefetched 1 deep); (a,d) in VGPRs;
// aliveness tracked as a 64-bit ballot mask (VALU: 2 v_cmp/dim, SALU ands).
__global__ __launch_bounds__(256) void fuzzy_kernel(
    const float* __restrict__ x, const float4* __restrict__ abcd,
    const float* __restrict__ rho, float* __restrict__ out) {
  __shared__ float accn[KB], accd[KB];
  const int tid = threadIdx.x;
  if (tid < KB) { accn[tid] = 0.0f; accd[tid] = 0.0f; }
  __syncthreads();

  const int r = tid;

  // One-time: support interval (a,d) for dims 0..15 -> registers.
  float av[16], dv[16];
#pragma unroll
  for (int i = 0; i < 16; ++i) {
    float4 v = abcd[r * A_N + i];
    av[i] = fminf(fminf(v.x, v.y), fminf(v.z, v.w));
    dv[i] = fmaxf(fmaxf(v.x, v.y), fmaxf(v.z, v.w));
  }

  const int k0 = blockIdx.x * KB;
  const float4* __restrict__ xbase =
      reinterpret_cast<const float4*>(x + (size_t)k0 * A_N);

  // Prefetch x[k0] dims 0..15 (uniform -> s_load_dwordx4).
  float4 xn0 = xbase[0], xn1 = xbase[1], xn2 = xbase[2], xn3 = xbase[3];

#pragma unroll 1
  for (int kk = 0; kk < KB; ++kk) {
    float4 x0 = xn0, x1 = xn1, x2 = xn2, x3 = xn3;
    {  // prefetch next k (clamped; uniform branch-free)
      int kn = (kk + 1 < KB) ? kk + 1 : kk;
      const float4* xf = xbase + kn * (A_N / 4);
      xn0 = xf[0]; xn1 = xf[1]; xn2 = xf[2]; xn3 = xf[3];
    }

#define C(xi, i) (int)((xi > av[i]) & (xi < dv[i]))
    unsigned long long alive;
    // dims 0..7 (P(wave alive) ~ 66%)
    alive  = __ballot(C(x0.x, 0) & C(x0.y, 1));
    alive &= __ballot(C(x0.z, 2) & C(x0.w, 3));
    alive &= __ballot(C(x1.x, 4) & C(x1.y, 5));
    alive &= __ballot(C(x1.z, 6) & C(x1.w, 7));
    if (!alive) continue;
    // dims 8..11 (P ~ 13%)
    alive &= __ballot(C(x2.x, 8) & C(x2.y, 9));
    alive &= __ballot(C(x2.z, 10) & C(x2.w, 11));
    if (!alive) continue;
    // dims 12..15 (P ~ 1.8%)
    alive &= __ballot(C(x3.x, 12) & C(x3.y, 13));
    alive &= __ballot(C(x3.z, 14) & C(x3.w, 15));
    if (!alive) continue;
#undef C

    // Cold: dims 16..63, lazy per-lane loads, mask check every 4 dims.
    const float* __restrict__ xr = x + (size_t)(k0 + kk) * A_N;  // uniform
    int g = 4;
#pragma unroll 1
    for (; g < 16; ++g) {
#pragma unroll
      for (int j = 0; j < 4; ++j) {
        float4 v = abcd[r * A_N + g * 4 + j];
        float a = fminf(fminf(v.x, v.y), fminf(v.z, v.w));
        float d = fmaxf(fmaxf(v.x, v.y), fmaxf(v.z, v.w));
        float xx = xr[g * 4 + j];
        alive &= __ballot((int)((xx > a) & (xx < d)));
      }
      if (!alive) break;
    }
    if (g < 16) continue;

    // Ultra-cold: some lane has w > 0. Exact evaluation (full sort + slopes).
    float w = 1.0f;
#pragma unroll 1
    for (int i = 0; i < A_N; ++i) {
      float4 v = abcd[r * A_N + i];
      float lo01 = fminf(v.x, v.y), hi01 = fmaxf(v.x, v.y);
      float lo23 = fminf(v.z, v.w), hi23 = fmaxf(v.z, v.w);
      float a = fminf(lo01, lo23), d = fmaxf(hi01, hi23);
      float t1 = fmaxf(lo01, lo23), t2 = fminf(hi01, hi23);
      float b = fminf(t1, t2), c = fmaxf(t1, t2);
      float xx = xr[i];
      float rise = (xx - a) / (b - a);
      float fall = (d - xx) / (d - c);
      w *= fmaxf(fminf(fminf(rise, 1.0f), fall), 0.0f);
    }
    if (w > 0.0f) {
      const float* __restrict__ rr = rho + r * (A_N + 1);
      float z = rr[A_N];
#pragma unroll 1
      for (int i = 0; i < A_N; ++i) z = fmaf(xr[i], rr[i], z);
      atomicAdd(&accn[kk], z * w);
      atomicAdd(&accd[kk], w);
    }
  }

  __syncthreads();
  if (tid < KB) out[k0 + tid] = accn[tid] / (accd[tid] + 1e-13f);
}

extern "C" void kernel_launch(void* const* d_in, const int* in_sizes, int n_in,
                              void* d_out, int out_size, void* d_ws, size_t ws_size,
                              hipStream_t stream) {
  const float* x = (const float*)d_in[0];
  const float4* abcd = (const float4*)d_in[1];
  const float* rho = (const float*)d_in[2];
  float* out = (float*)d_out;

  hipLaunchKernelGGL(fuzzy_kernel, dim3(B_N / KB), dim3(256), 0, stream,
                     x, abcd, rho, out);
}